// Round 1
// baseline (11.384 us; speedup 1.0000x reference)
//
#include <hip/hip_runtime.h>

#define W 256  // window size == block size == workgroup size

__global__ __launch_bounds__(W) void slidemin_kernel(const float* __restrict__ sig,
                                                     float* __restrict__ out,
                                                     int T) {
    __shared__ float s[2 * W];
    const int t = threadIdx.x;
    const int base = blockIdx.x * W;
    const int g0 = base + t;
    const int g1 = g0 + W;

    // padding='last' == clamp index to T-1
    s[t]     = sig[g0 < T ? g0 : T - 1];
    s[W + t] = sig[g1 < T ? g1 : T - 1];
    __syncthreads();

    // s[0..W-1]   -> suffix-min of block k   : s[i] = min(blk[i..W-1])
    // s[W..2W-1]  -> prefix-min of block k+1 : s[W+j] = min(blk1[0..j])
    #pragma unroll
    for (int off = 1; off < W; off <<= 1) {
        float a = s[t];
        float b = (t + off < W) ? s[t + off] : a;
        float c = s[W + t];
        float d = (t >= off) ? s[W + t - off] : c;
        __syncthreads();
        s[t]     = fminf(a, b);
        s[W + t] = fminf(c, d);
        __syncthreads();
    }

    if (g0 < T) {
        // window [g0, g0+255]: suffix of block k from t, plus (if t>0)
        // prefix of block k+1 up to t-1
        float v = (t == 0) ? s[0] : fminf(s[t], s[W + t - 1]);
        out[g0] = v;
    }
}

extern "C" void kernel_launch(void* const* d_in, const int* in_sizes, int n_in,
                              void* d_out, int out_size, void* d_ws, size_t ws_size,
                              hipStream_t stream) {
    const float* sig = (const float*)d_in[0];
    float* out = (float*)d_out;
    const int T = in_sizes[0];
    const int nblk = (T + W - 1) / W;
    slidemin_kernel<<<nblk, W, 0, stream>>>(sig, out, T);
}

// Round 2
// 10.093 us; speedup vs baseline: 1.1280x; 1.1280x over previous
//
#include <hip/hip_runtime.h>
#include <math.h>

#define SEG 256                 // window size == segment size
#define WAVES_PER_BLOCK 4
#define BLOCK (WAVES_PER_BLOCK * 64)

// out[t] = min(sig[t .. t+255]) with clamp-to-last padding.
// van Herk decomposition at segment granularity 256:
//   out[t] = min( suffix_min(seg s from t), prefix_min(seg s+1 up to t-1) )
// One 64-lane wave per segment; 4 elements per lane; all cross-lane work
// via shuffles (no LDS, no barriers).
__global__ __launch_bounds__(BLOCK) void slidemin_wave(const float* __restrict__ sig,
                                                       float* __restrict__ out,
                                                       int T, int nseg) {
    const int lane = threadIdx.x & 63;
    const int wid  = threadIdx.x >> 6;
    const int seg  = blockIdx.x * WAVES_PER_BLOCK + wid;
    if (seg >= nseg) return;

    const int base = seg * SEG;
    const int g0 = base + lane * 4;   // own segment, 16B-aligned
    const int g1 = g0 + SEG;          // next segment

    float a0, a1, a2, a3, b0, b1, b2, b3;
    if (g1 + 3 < T) {                 // fast path: both float4 loads in-bounds
        float4 va = *reinterpret_cast<const float4*>(sig + g0);
        float4 vb = *reinterpret_cast<const float4*>(sig + g1);
        a0 = va.x; a1 = va.y; a2 = va.z; a3 = va.w;
        b0 = vb.x; b1 = vb.y; b2 = vb.z; b3 = vb.w;
    } else {                          // tail: clamp index (padding='last')
        const int tm1 = T - 1;
        a0 = sig[g0 + 0 < T ? g0 + 0 : tm1];
        a1 = sig[g0 + 1 < T ? g0 + 1 : tm1];
        a2 = sig[g0 + 2 < T ? g0 + 2 : tm1];
        a3 = sig[g0 + 3 < T ? g0 + 3 : tm1];
        b0 = sig[g1 + 0 < T ? g1 + 0 : tm1];
        b1 = sig[g1 + 1 < T ? g1 + 1 : tm1];
        b2 = sig[g1 + 2 < T ? g1 + 2 : tm1];
        b3 = sig[g1 + 3 < T ? g1 + 3 : tm1];
    }

    // local suffix mins of own segment chunk
    float ls3 = a3;
    float ls2 = fminf(a2, ls3);
    float ls1 = fminf(a1, ls2);
    float ls0 = fminf(a0, ls1);
    // local prefix mins of next-segment chunk
    float lp0 = b0;
    float lp1 = fminf(lp0, b1);
    float lp2 = fminf(lp1, b2);
    float lp3 = fminf(lp2, b3);

    // wave inclusive suffix-scan of full-lane min (lanes high -> low)
    float A = ls0;
    #pragma unroll
    for (int off = 1; off < 64; off <<= 1) {
        float u = __shfl_down(A, off, 64);
        if (lane + off < 64) A = fminf(A, u);
    }
    float sExcl = __shfl_down(A, 1, 64);      // min over lanes > l
    if (lane == 63) sExcl = INFINITY;

    // wave inclusive prefix-scan of full-lane min of b (lanes low -> high)
    float B = lp3;
    #pragma unroll
    for (int off = 1; off < 64; off <<= 1) {
        float u = __shfl_up(B, off, 64);
        if (lane >= off) B = fminf(B, u);
    }
    float pExcl = __shfl_up(B, 1, 64);        // min over lanes < l
    if (lane == 0) pExcl = INFINITY;

    // suffix of seg s starting at each of this lane's 4 positions
    float s0 = fminf(ls0, sExcl);
    float s1 = fminf(ls1, sExcl);
    float s2 = fminf(ls2, sExcl);
    float s3 = fminf(ls3, sExcl);

    // combine with prefix of seg s+1 up to (pos-1)
    float4 o;
    o.x = fminf(s0, pExcl);                   // r=0: no local b part
    o.y = fminf(s1, fminf(pExcl, lp0));
    o.z = fminf(s2, fminf(pExcl, lp1));
    o.w = fminf(s3, fminf(pExcl, lp2));

    if (g0 + 3 < T) {
        *reinterpret_cast<float4*>(out + g0) = o;
    } else {
        if (g0 + 0 < T) out[g0 + 0] = o.x;
        if (g0 + 1 < T) out[g0 + 1] = o.y;
        if (g0 + 2 < T) out[g0 + 2] = o.z;
        if (g0 + 3 < T) out[g0 + 3] = o.w;
    }
}

extern "C" void kernel_launch(void* const* d_in, const int* in_sizes, int n_in,
                              void* d_out, int out_size, void* d_ws, size_t ws_size,
                              hipStream_t stream) {
    const float* sig = (const float*)d_in[0];
    float* out = (float*)d_out;
    const int T = in_sizes[0];
    const int nseg = (T + SEG - 1) / SEG;
    const int nblk = (nseg + WAVES_PER_BLOCK - 1) / WAVES_PER_BLOCK;
    slidemin_wave<<<nblk, BLOCK, 0, stream>>>(sig, out, T, nseg);
}

// Round 3
// 9.995 us; speedup vs baseline: 1.1391x; 1.0098x over previous
//
#include <hip/hip_runtime.h>
#include <math.h>

#define SEG 256                 // window size == segment size
#define WAVES_PER_BLOCK 4
#define BLOCK (WAVES_PER_BLOCK * 64)

// out[t] = min(sig[t .. t+255]) with clamp-to-last padding.
// van Herk decomposition at segment granularity 256:
//   out[t] = min( suffix_min(seg s from t), prefix_min(seg s+1 up to t-1) )
// One 64-lane wave per segment; 4 elements per lane; all cross-lane work
// via shuffles (no LDS, no barriers).
//
// Scan steps are UNGUARDED: HIP __shfl_down/__shfl_up return the lane's own
// value when the source lane is out of range, and fminf is idempotent, so
// min(A, shfl(A)) is a no-op for OOB lanes — no cndmask needed.
__global__ __launch_bounds__(BLOCK) void slidemin_wave(const float* __restrict__ sig,
                                                       float* __restrict__ out,
                                                       int T, int nseg) {
    const int lane = threadIdx.x & 63;
    const int wid  = threadIdx.x >> 6;
    const int seg  = blockIdx.x * WAVES_PER_BLOCK + wid;
    if (seg >= nseg) return;

    const int base = seg * SEG;
    const int g0 = base + lane * 4;   // own segment, 16B-aligned
    const int g1 = g0 + SEG;          // next segment

    float a0, a1, a2, a3, b0, b1, b2, b3;
    if (g1 + 3 < T) {                 // fast path: both float4 loads in-bounds
        float4 va = *reinterpret_cast<const float4*>(sig + g0);
        float4 vb = *reinterpret_cast<const float4*>(sig + g1);
        a0 = va.x; a1 = va.y; a2 = va.z; a3 = va.w;
        b0 = vb.x; b1 = vb.y; b2 = vb.z; b3 = vb.w;
    } else {                          // tail: clamp index (padding='last')
        const int tm1 = T - 1;
        a0 = sig[g0 + 0 < T ? g0 + 0 : tm1];
        a1 = sig[g0 + 1 < T ? g0 + 1 : tm1];
        a2 = sig[g0 + 2 < T ? g0 + 2 : tm1];
        a3 = sig[g0 + 3 < T ? g0 + 3 : tm1];
        b0 = sig[g1 + 0 < T ? g1 + 0 : tm1];
        b1 = sig[g1 + 1 < T ? g1 + 1 : tm1];
        b2 = sig[g1 + 2 < T ? g1 + 2 : tm1];
        b3 = sig[g1 + 3 < T ? g1 + 3 : tm1];
    }

    // local suffix mins of own segment chunk
    float ls3 = a3;
    float ls2 = fminf(a2, ls3);
    float ls1 = fminf(a1, ls2);
    float ls0 = fminf(a0, ls1);
    // local prefix mins of next-segment chunk
    float lp0 = b0;
    float lp1 = fminf(lp0, b1);
    float lp2 = fminf(lp1, b2);
    float lp3 = fminf(lp2, b3);

    // wave inclusive suffix-scan (lanes high -> low), unguarded
    float A = ls0;
    #pragma unroll
    for (int off = 1; off < 64; off <<= 1)
        A = fminf(A, __shfl_down(A, off, 64));
    float sExcl = __shfl_down(A, 1, 64);      // min over lanes > l
    sExcl = (lane == 63) ? INFINITY : sExcl;

    // wave inclusive prefix-scan (lanes low -> high), unguarded
    float B = lp3;
    #pragma unroll
    for (int off = 1; off < 64; off <<= 1)
        B = fminf(B, __shfl_up(B, off, 64));
    float pExcl = __shfl_up(B, 1, 64);        // min over lanes < l
    pExcl = (lane == 0) ? INFINITY : pExcl;

    // suffix of seg s starting at each of this lane's 4 positions
    float s0 = fminf(ls0, sExcl);
    float s1 = fminf(ls1, sExcl);
    float s2 = fminf(ls2, sExcl);
    float s3 = fminf(ls3, sExcl);

    // combine with prefix of seg s+1 up to (pos-1); fuses to v_min3_f32
    float4 o;
    o.x = fminf(s0, pExcl);                   // r=0: no local b part
    o.y = fminf(s1, fminf(pExcl, lp0));
    o.z = fminf(s2, fminf(pExcl, lp1));
    o.w = fminf(s3, fminf(pExcl, lp2));

    if (g0 + 3 < T) {
        *reinterpret_cast<float4*>(out + g0) = o;
    } else {
        if (g0 + 0 < T) out[g0 + 0] = o.x;
        if (g0 + 1 < T) out[g0 + 1] = o.y;
        if (g0 + 2 < T) out[g0 + 2] = o.z;
        if (g0 + 3 < T) out[g0 + 3] = o.w;
    }
}

extern "C" void kernel_launch(void* const* d_in, const int* in_sizes, int n_in,
                              void* d_out, int out_size, void* d_ws, size_t ws_size,
                              hipStream_t stream) {
    const float* sig = (const float*)d_in[0];
    float* out = (float*)d_out;
    const int T = in_sizes[0];
    const int nseg = (T + SEG - 1) / SEG;
    const int nblk = (nseg + WAVES_PER_BLOCK - 1) / WAVES_PER_BLOCK;
    slidemin_wave<<<nblk, BLOCK, 0, stream>>>(sig, out, T, nseg);
}